// Round 10
// baseline (146.457 us; speedup 1.0000x reference)
//
#include <hip/hip_runtime.h>

// SAGEConv-mean: out[n,:] = (sum_{e: dst[e]==n} x[src[e],:]) / deg[n] @ W^T + b
// N=100000, E=1000000, D=64, fp32 in/out.
//
// Round 20: partition-parallelism round. Ledger: harness ~76us (poison fill
// 44.7 + restores/gaps), gather ~36us (random-read ceiling; 5 falsification
// tests), partition_xw ~25us. r19 (MFMA xw) neutral -> xw compute not
// binding; partition half is the long pole: 123x 8192-edge blocks on 123
// CUs (~60K cy each of LDS-atomic + scattered-write serialization) while
// the other half of the machine idles after xw (~8us). Change vs r19:
//   - partition block = 4096 edges (245 blocks ~ one per CU, each co-
//     resident with ~3 xw blocks; VALU xw overlaps TA/LDS-atomic partition).
//     Per-block serialized content halves. Reserve atomics 190K -> ~320K
//     (205/address, acceptable). Gather/xw/launcher otherwise untouched.
//   pred: partition_xw 25 -> 16-19us, dur 140 -> ~131-134; absmax 0.015625;
//   if neutral: long-pole theory wrong too -> declare ~140 as floor.
// Chain: memset(8KB cursors) -> partition_xw -> bucket_gather (3 dispatches).
// Fallback: atomic scatter + LDS GEMM (ws too small or N too big or nb > MAXB).

#define D 64
#define BSHIFT 6                  // 64 nodes per bucket
#define BNODES (1 << BSHIFT)
#define CAP 1024                  // static slots per bucket (mean fill 640, +15 sigma)
#define GTHREADS 512
#define PERTHREAD (CAP / GTHREADS)   // 2
#define PXW_THREADS 512
#define PEDGES 4096               // edges per partition block (8 per thread)
#define MAXB 2048                 // max buckets supported by partition LDS

typedef __attribute__((ext_vector_type(8))) short bf16x8;
typedef __attribute__((ext_vector_type(4))) float f32x4;

// Per-block edge-dtype detect: int64 little-endian => odd 32-bit words are zero
// high-halves. 64 samples -> P(false int32 hit) ~ (1/N)^64 ~ 0.
__device__ inline int detect_stride_block(const unsigned* __restrict__ words,
                                          int E, int* sflag) {
    int t = threadIdx.x;
    if (t < 64) {
        unsigned v = (t < E) ? words[2 * t + 1] : 0u;
        int any = __any(v != 0u);
        if (t == 0) *sflag = any ? 1 : 2;   // word stride: 1=int32, 2=int64
    }
    __syncthreads();
    return *sflag;
}

__device__ inline unsigned pack_bf16(float a, float b) {   // two fp32 -> bf16x2, RNE
    unsigned ua = __float_as_uint(a), ub = __float_as_uint(b);
    ua += 0x7fffu + ((ua >> 16) & 1u);
    ub += 0x7fffu + ((ub >> 16) & 1u);
    return (ua >> 16) | (ub & 0xffff0000u);
}

__device__ inline bf16x8 mk_frag(unsigned u0, unsigned u1,
                                 unsigned u2, unsigned u3) {
    union { unsigned u[4]; bf16x8 v; } r;
    r.u[0] = u0; r.u[1] = u1; r.u[2] = u2; r.u[3] = u3;
    return r.v;
}

// ---- fused partition (blocks [0,pblocks)) + MFMA xw (rest), 512 thr -----
__global__ __launch_bounds__(PXW_THREADS, 4) void partition_xw_kernel(
        const unsigned* __restrict__ ewords, int* __restrict__ cursor,
        unsigned* __restrict__ pairs, uint2* __restrict__ spill,
        int* __restrict__ spillCnt,
        const float* __restrict__ x, const float* __restrict__ W,
        unsigned* __restrict__ y2, int E, int N, int nb, int pblocks) {
    __shared__ __align__(16) char smem[16400];   // partition only: 2*MAXB*4 + 4
    int t = threadIdx.x;

    if ((int)blockIdx.x < pblocks) {
        // ---------------- partition: 4096 edges, one pass ----------------
        int* lhist = (int*)smem;
        int* lbase = lhist + MAXB;
        int* sflag = lbase + MAXB;
        int s = detect_stride_block(ewords, E, sflag);
        int base = blockIdx.x * PEDGES;
        for (int i = t; i < nb; i += PXW_THREADS) lhist[i] = 0;
        __syncthreads();
        unsigned pv[8]; int bk[8];
        #pragma unroll
        for (int k = 0; k < 8; ++k) {
            int e = base + k * PXW_THREADS + t;
            bk[k] = -1;
            if (e < E) {
                unsigned src = ewords[(size_t)e * s];
                unsigned dst = ewords[((size_t)E + e) * s];
                bk[k] = (int)(dst >> BSHIFT);
                pv[k] = src | ((dst & (BNODES - 1)) << 17);
                atomicAdd(&lhist[bk[k]], 1);
            }
        }
        __syncthreads();
        for (int hb = t; hb < nb; hb += PXW_THREADS) {
            int cc = lhist[hb];
            if (cc) lbase[hb] = atomicAdd(&cursor[hb], cc);
            lhist[hb] = 0;                    // reuse as running cursor
        }
        __syncthreads();
        #pragma unroll
        for (int k = 0; k < 8; ++k) {
            if (bk[k] >= 0) {
                int lpos = lbase[bk[k]] + atomicAdd(&lhist[bk[k]], 1);
                if (lpos < CAP) {
                    pairs[(size_t)bk[k] * CAP + lpos] = pv[k];
                } else {                      // overflow (never for this input)
                    int si = atomicAdd(spillCnt, 1);
                    unsigned dst = ((unsigned)bk[k] << BSHIFT) | (pv[k] >> 17);
                    spill[si] = make_uint2(pv[k] & 0x1FFFFu, dst);
                }
            }
        }
    } else {
        // -------- xw via MFMA: D = W x^T, 128-node tile, y -> bf16 -------
        // wave w owns node-tile w (nodes base+16w .. +15). Per lane l:
        //   A-frag: W[ot*16 + (l&15)][kh*32 + (l>>4)*8 + j]   (A row = l&15)
        //   B-frag: x[base+16w + (l&15)][kh*32 + (l>>4)*8 + j] (B col = l&15)
        //   D:      out = ot*16 + (l>>4)*4 + r,  node = base+16w + (l&15)
        int l = t & 63, w = t >> 6;
        int rowi = l & 15, kq = l >> 4;
        int base = ((int)blockIdx.x - pblocks) * 128;
        int n = base + w * 16 + rowi;
        bf16x8 bfrag[2];
        #pragma unroll
        for (int kh = 0; kh < 2; ++kh) {
            float4 f0 = {0.f, 0.f, 0.f, 0.f}, f1 = {0.f, 0.f, 0.f, 0.f};
            if (n < N) {
                const float* xp = x + (size_t)n * 64 + kh * 32 + kq * 8;
                f0 = *(const float4*)xp;
                f1 = *(const float4*)(xp + 4);
            }
            bfrag[kh] = mk_frag(pack_bf16(f0.x, f0.y), pack_bf16(f0.z, f0.w),
                                pack_bf16(f1.x, f1.y), pack_bf16(f1.z, f1.w));
        }
        f32x4 acc0 = {0.f, 0.f, 0.f, 0.f}, acc1 = acc0, acc2 = acc0, acc3 = acc0;
        #pragma unroll
        for (int kh = 0; kh < 2; ++kh) {
            const float* wp = W + rowi * 64 + kh * 32 + kq * 8;
            float4 g0, g1;
            g0 = *(const float4*)(wp);            // ot = 0
            g1 = *(const float4*)(wp + 4);
            acc0 = __builtin_amdgcn_mfma_f32_16x16x32_bf16(
                mk_frag(pack_bf16(g0.x, g0.y), pack_bf16(g0.z, g0.w),
                        pack_bf16(g1.x, g1.y), pack_bf16(g1.z, g1.w)),
                bfrag[kh], acc0, 0, 0, 0);
            g0 = *(const float4*)(wp + 16 * 64);  // ot = 1
            g1 = *(const float4*)(wp + 16 * 64 + 4);
            acc1 = __builtin_amdgcn_mfma_f32_16x16x32_bf16(
                mk_frag(pack_bf16(g0.x, g0.y), pack_bf16(g0.z, g0.w),
                        pack_bf16(g1.x, g1.y), pack_bf16(g1.z, g1.w)),
                bfrag[kh], acc1, 0, 0, 0);
            g0 = *(const float4*)(wp + 32 * 64);  // ot = 2
            g1 = *(const float4*)(wp + 32 * 64 + 4);
            acc2 = __builtin_amdgcn_mfma_f32_16x16x32_bf16(
                mk_frag(pack_bf16(g0.x, g0.y), pack_bf16(g0.z, g0.w),
                        pack_bf16(g1.x, g1.y), pack_bf16(g1.z, g1.w)),
                bfrag[kh], acc2, 0, 0, 0);
            g0 = *(const float4*)(wp + 48 * 64);  // ot = 3
            g1 = *(const float4*)(wp + 48 * 64 + 4);
            acc3 = __builtin_amdgcn_mfma_f32_16x16x32_bf16(
                mk_frag(pack_bf16(g0.x, g0.y), pack_bf16(g0.z, g0.w),
                        pack_bf16(g1.x, g1.y), pack_bf16(g1.z, g1.w)),
                bfrag[kh], acc3, 0, 0, 0);
        }
        if (n < N) {
            unsigned* yp = y2 + (size_t)n * 32 + kq * 2;
            uint2 p;
            p.x = pack_bf16(acc0[0], acc0[1]);
            p.y = pack_bf16(acc0[2], acc0[3]);
            *(uint2*)(yp) = p;                    // outs 0..15 quad
            p.x = pack_bf16(acc1[0], acc1[1]);
            p.y = pack_bf16(acc1[2], acc1[3]);
            *(uint2*)(yp + 8) = p;                // outs 16..31 quad
            p.x = pack_bf16(acc2[0], acc2[1]);
            p.y = pack_bf16(acc2[2], acc2[3]);
            *(uint2*)(yp + 16) = p;               // outs 32..47 quad
            p.x = pack_bf16(acc3[0], acc3[1]);
            p.y = pack_bf16(acc3[2], acc3[3]);
            *(uint2*)(yp + 24) = p;               // outs 48..63 quad
        }
    }
}

// accumulate one uint4 (8 bf16 cols) into register set S
#define RACC8(S, u) { \
    S[0] += __uint_as_float((u).x << 16); \
    S[1] += __uint_as_float((u).x & 0xffff0000u); \
    S[2] += __uint_as_float((u).y << 16); \
    S[3] += __uint_as_float((u).y & 0xffff0000u); \
    S[4] += __uint_as_float((u).z << 16); \
    S[5] += __uint_as_float((u).z & 0xffff0000u); \
    S[6] += __uint_as_float((u).w << 16); \
    S[7] += __uint_as_float((u).w & 0xffff0000u); }

// ---- bucket gather: counting-sort + 4-deep register gather --------------
__global__ __launch_bounds__(GTHREADS) void bucket_gather(
        const unsigned* __restrict__ y2, const unsigned* __restrict__ pairs,
        const int* __restrict__ cursor, const uint2* __restrict__ spill,
        const int* __restrict__ spillCnt,
        const float* __restrict__ deg, const float* __restrict__ b,
        float* __restrict__ out, int N) {
    __shared__ unsigned list[CAP];           // sorted srcs, 4 KB
    __shared__ int cnt[BNODES], st[BNODES], sc[BNODES];
    int t = threadIdx.x;
    int bkt = blockIdx.x, base = bkt << BSHIFT;
    int total = cursor[bkt];
    int cn = total < CAP ? total : CAP;      // slots [0,cn) valid; rest spilled
    int node = t >> 3, c = t & 7;            // 64 nodes x 8 col-octs = 512
    float4 bv0 = ((const float4*)b)[c * 2];
    float4 bv1 = ((const float4*)b)[c * 2 + 1];

    if (t < BNODES) cnt[t] = 0;
    __syncthreads();
    unsigned pv[PERTHREAD];
    #pragma unroll
    for (int j = 0; j < PERTHREAD; ++j) {             // one coalesced pass
        int i = t + j * GTHREADS;
        pv[j] = (i < cn) ? pairs[(size_t)bkt * CAP + i] : 0xFFFFFFFFu;
        if (pv[j] != 0xFFFFFFFFu) atomicAdd(&cnt[pv[j] >> 17], 1);
    }
    __syncthreads();
    if (t < 64) {                            // 64-bin exclusive scan, one wave
        int v = cnt[t];
        #pragma unroll
        for (int off = 1; off < 64; off <<= 1) {
            int u = __shfl_up(v, off);
            if (t >= off) v += u;
        }
        st[t] = v - cnt[t]; sc[t] = v - cnt[t];
    }
    __syncthreads();
    #pragma unroll
    for (int j = 0; j < PERTHREAD; ++j) {             // scatter from registers
        if (pv[j] != 0xFFFFFFFFu) {
            int pos = atomicAdd(&sc[pv[j] >> 17], 1);
            list[pos] = pv[j] & 0x1FFFFu;             // src only
        }
    }
    __syncthreads();

    int scnt = *spillCnt;                             // 0 in practice

    int n = base + node;
    int s0 = st[node], e1 = s0 + cnt[node];
    float sa[8], sb[8], sc_[8], sd[8];
    #pragma unroll
    for (int k = 0; k < 8; ++k) { sa[k] = 0.f; sb[k] = 0.f; sc_[k] = 0.f; sd[k] = 0.f; }
    int i = s0;
    for (; i + 3 < e1; i += 4) {                      // 4 loads in flight
        unsigned v0 = list[i], v1 = list[i + 1];
        unsigned v2 = list[i + 2], v3 = list[i + 3];
        uint4 u0 = *(const uint4*)(y2 + (size_t)v0 * 32 + c * 4);
        uint4 u1 = *(const uint4*)(y2 + (size_t)v1 * 32 + c * 4);
        uint4 u2 = *(const uint4*)(y2 + (size_t)v2 * 32 + c * 4);
        uint4 u3 = *(const uint4*)(y2 + (size_t)v3 * 32 + c * 4);
        RACC8(sa, u0);
        RACC8(sb, u1);
        RACC8(sc_, u2);
        RACC8(sd, u3);
    }
    if (i + 1 < e1) {                                 // pair tail
        unsigned v0 = list[i], v1 = list[i + 1];
        uint4 u0 = *(const uint4*)(y2 + (size_t)v0 * 32 + c * 4);
        uint4 u1 = *(const uint4*)(y2 + (size_t)v1 * 32 + c * 4);
        RACC8(sa, u0);
        RACC8(sb, u1);
        i += 2;
    }
    if (i < e1) {                                     // single tail
        unsigned v0 = list[i];
        uint4 u0 = *(const uint4*)(y2 + (size_t)v0 * 32 + c * 4);
        RACC8(sa, u0);
    }
    #pragma unroll
    for (int k = 0; k < 8; ++k) sa[k] = (sa[k] + sb[k]) + (sc_[k] + sd[k]);
    for (int k = 0; k < scnt; ++k) {                  // overflow path (empty)
        uint2 e = spill[k];
        if ((int)e.y == n) {
            uint4 u = *(const uint4*)(y2 + (size_t)e.x * 32 + c * 4);
            RACC8(sa, u);
        }
    }
    if (n < N) {
        float invd = 1.0f / deg[n];
        float4 o0 = {sa[0] * invd + bv0.x, sa[1] * invd + bv0.y,
                     sa[2] * invd + bv0.z, sa[3] * invd + bv0.w};
        float4 o1 = {sa[4] * invd + bv1.x, sa[5] * invd + bv1.y,
                     sa[6] * invd + bv1.z, sa[7] * invd + bv1.w};
        *(float4*)(out + (size_t)n * 64 + c * 8) = o0;
        *(float4*)(out + (size_t)n * 64 + c * 8 + 4) = o1;
    }
}

// ---- fallback: atomic scatter + LDS GEMM --------------------------------
__global__ __launch_bounds__(256) void scatter_kernel(
        const float* __restrict__ x, const unsigned* __restrict__ ewords,
        float* __restrict__ agg, int E) {
    __shared__ int sflag;
    int s = detect_stride_block(ewords, E, &sflag);
    int gid = blockIdx.x * blockDim.x + threadIdx.x;
    int e = gid >> 4, q = gid & 15;
    if (e >= E) return;
    int src = (int)ewords[(size_t)e * s];
    int dst = (int)ewords[((size_t)E + e) * s];
    const float4 v = *(const float4*)(x + (size_t)src * D + q * 4);
    float* p = agg + (size_t)dst * D + q * 4;
    unsafeAtomicAdd(p + 0, v.x);
    unsafeAtomicAdd(p + 1, v.y);
    unsafeAtomicAdd(p + 2, v.z);
    unsafeAtomicAdd(p + 3, v.w);
}

__global__ __launch_bounds__(256) void gemm_kernel(
        float* __restrict__ inout, const float* __restrict__ deg,
        const float* __restrict__ W, const float* __restrict__ b, int nNodes) {
    __shared__ float Wt[64 * 65];
    __shared__ float rows[4 * 64];
    int t = threadIdx.x;
    for (int i = t; i < 64 * 64; i += 256) {
        int o = i >> 6, k = i & 63;
        Wt[k * 65 + o] = W[i];
    }
    int base = blockIdx.x * 4;
    int nl = t >> 6, o = t & 63;
    int n = base + nl;
    if (n < nNodes) {
        float invd = 1.0f / deg[n];
        rows[nl * 64 + o] = inout[(size_t)n * 64 + o] * invd;
    }
    __syncthreads();
    if (n >= nNodes) return;
    float acc = b[o];
    #pragma unroll
    for (int k = 0; k < 64; ++k)
        acc += rows[nl * 64 + k] * Wt[k * 65 + o];
    inout[(size_t)n * 64 + o] = acc;
}

extern "C" void kernel_launch(void* const* d_in, const int* in_sizes, int n_in,
                              void* d_out, int out_size, void* d_ws, size_t ws_size,
                              hipStream_t stream) {
    const float*    x      = (const float*)d_in[0];
    const unsigned* ewords = (const unsigned*)d_in[1];
    const float*    deg    = (const float*)d_in[2];
    const float*    W      = (const float*)d_in[3];
    const float*    b      = (const float*)d_in[4];
    float*          out    = (float*)d_out;

    const int E = in_sizes[1] / 2;
    const int N = in_sizes[2];
    const int nb = (N + BNODES - 1) >> BSHIFT;         // 1563 for N=100000

    // ws layout: cursor[MAXB] + spillCnt | pairs[nb*CAP] | spill[E] | y2[N*32]
    char* ws = (char*)d_ws;
    size_t curB  = (MAXB + 16) * 4;
    size_t pairB = ((size_t)nb * CAP * 4 + 63) & ~63ull;
    size_t spB   = ((size_t)E * 8 + 63) & ~63ull;
    size_t need  = curB + pairB + spB + (size_t)N * 32 * 4;

    if (ws_size >= need && N < (1 << 17) && nb <= MAXB) {
        int*      cursor   = (int*)ws;
        int*      spillCnt = cursor + MAXB;
        unsigned* pairs    = (unsigned*)(ws + curB);
        uint2*    spill    = (uint2*)(ws + curB + pairB);
        unsigned* y2       = (unsigned*)(ws + curB + pairB + spB);

        hipMemsetAsync(cursor, 0, curB, stream);       // 8KB: cursors + spillCnt

        int pblocks  = (E + PEDGES - 1) / PEDGES;      // 245 for E=1M
        int xwblocks = (N + 127) / 128;
        partition_xw_kernel<<<pblocks + xwblocks, PXW_THREADS, 0, stream>>>(
            ewords, cursor, pairs, spill, spillCnt, x, W, y2, E, N, nb, pblocks);

        bucket_gather<<<nb, GTHREADS, 0, stream>>>(
            y2, pairs, cursor, spill, spillCnt, deg, b, out, N);
    } else {
        hipMemsetAsync(d_out, 0, (size_t)out_size * sizeof(float), stream);
        long long sthreads = (long long)E * 16;
        int sblocks = (int)((sthreads + 255) / 256);
        scatter_kernel<<<sblocks, 256, 0, stream>>>(x, ewords, out, E);
        gemm_kernel<<<(N + 3) / 4, 256, 0, stream>>>(out, deg, W, b, N);
    }
}

// Round 11
// 140.158 us; speedup vs baseline: 1.0449x; 1.0449x over previous
//
#include <hip/hip_runtime.h>

// SAGEConv-mean: out[n,:] = (sum_{e: dst[e]==n} x[src[e],:]) / deg[n] @ W^T + b
// N=100000, E=1000000, D=64, fp32 in/out (no fp32 MFMA -> VALU GEMM).
//
// Round 21: FINAL REVERT to best-measured artifact (r18 = 140.1us; r12
// structure + 4-deep gather; r12 measured 139.8 -- tied within noise).
// Falsification ledger (8 tests):
//   gather (36us): bucket 128/32/64 nodes, uint2->uint4, balanced-LDS x2
//     (80us, 378us -- LDS write paths lose to register accum), 4-deep MLP
//     -> random-read ceiling: FETCH 93MB = 8 XCDs x y2 12.8MB, ~2.6TB/s.
//   xw (8us): MFMA-bf16 swap -> neutral (compute not binding).
//   partition (16us): 8192->4096-edge blocks -> negative (cost = per-edge
//     LDS atomics + scattered pair writes, invariant to decomposition).
//   harness ~76us uncontrollable (45us 268MB ws-poison fill + restores).
// Controllable chain 64us vs ~50us of measured floors -> declare after
// reproduction.
// Chain: memset(8KB cursors) -> partition_xw -> bucket_gather (3 dispatches).
// Fallback: atomic scatter + LDS GEMM (ws too small or N too big or nb > MAXB).

#define D 64
#define BSHIFT 6                  // 64 nodes per bucket
#define BNODES (1 << BSHIFT)
#define CAP 1024                  // static slots per bucket (mean fill 640, +15 sigma)
#define GTHREADS 512
#define PERTHREAD (CAP / GTHREADS)   // 2
#define PXW_THREADS 512
#define MAXB 2048                 // max buckets supported by partition LDS

// Per-block edge-dtype detect: int64 little-endian => odd 32-bit words are zero
// high-halves. 64 samples -> P(false int32 hit) ~ (1/N)^64 ~ 0.
__device__ inline int detect_stride_block(const unsigned* __restrict__ words,
                                          int E, int* sflag) {
    int t = threadIdx.x;
    if (t < 64) {
        unsigned v = (t < E) ? words[2 * t + 1] : 0u;
        int any = __any(v != 0u);
        if (t == 0) *sflag = any ? 1 : 2;   // word stride: 1=int32, 2=int64
    }
    __syncthreads();
    return *sflag;
}

__device__ inline unsigned pack_bf16(float a, float b) {   // two fp32 -> bf16x2, RNE
    unsigned ua = __float_as_uint(a), ub = __float_as_uint(b);
    ua += 0x7fffu + ((ua >> 16) & 1u);
    ub += 0x7fffu + ((ub >> 16) & 1u);
    return (ua >> 16) | (ub & 0xffff0000u);
}

// ---- fused partition (blocks [0,pblocks)) + xw GEMM (rest), 512 thr -----
__global__ __launch_bounds__(PXW_THREADS, 4) void partition_xw_kernel(
        const unsigned* __restrict__ ewords, int* __restrict__ cursor,
        unsigned* __restrict__ pairs, uint2* __restrict__ spill,
        int* __restrict__ spillCnt,
        const float* __restrict__ x, const float* __restrict__ W,
        unsigned* __restrict__ y2, int E, int N, int nb, int pblocks) {
    __shared__ __align__(16) char smem[52240];   // xw 52224B | part 16388B
    int t = threadIdx.x;

    if ((int)blockIdx.x < pblocks) {
        // ---------------- partition: 8192 edges, one pass ----------------
        int* lhist = (int*)smem;
        int* lbase = lhist + MAXB;
        int* sflag = lbase + MAXB;
        int s = detect_stride_block(ewords, E, sflag);
        int base = blockIdx.x * 8192;
        for (int i = t; i < nb; i += PXW_THREADS) lhist[i] = 0;
        __syncthreads();
        unsigned pv[16]; int bk[16];
        #pragma unroll
        for (int k = 0; k < 16; ++k) {
            int e = base + k * PXW_THREADS + t;
            bk[k] = -1;
            if (e < E) {
                unsigned src = ewords[(size_t)e * s];
                unsigned dst = ewords[((size_t)E + e) * s];
                bk[k] = (int)(dst >> BSHIFT);
                pv[k] = src | ((dst & (BNODES - 1)) << 17);
                atomicAdd(&lhist[bk[k]], 1);
            }
        }
        __syncthreads();
        for (int hb = t; hb < nb; hb += PXW_THREADS) {
            int cc = lhist[hb];
            if (cc) lbase[hb] = atomicAdd(&cursor[hb], cc);
            lhist[hb] = 0;                    // reuse as running cursor
        }
        __syncthreads();
        #pragma unroll
        for (int k = 0; k < 16; ++k) {
            if (bk[k] >= 0) {
                int lpos = lbase[bk[k]] + atomicAdd(&lhist[bk[k]], 1);
                if (lpos < CAP) {
                    pairs[(size_t)bk[k] * CAP + lpos] = pv[k];
                } else {                      // overflow (never for this input)
                    int si = atomicAdd(spillCnt, 1);
                    unsigned dst = ((unsigned)bk[k] << BSHIFT) | (pv[k] >> 17);
                    spill[si] = make_uint2(pv[k] & 0x1FFFFu, dst);
                }
            }
        }
    } else {
        // ---------------- xw: 128-node tile, y = x @ W^T -> bf16 ---------
        float* Wt = (float*)smem;                 // Wt[k*68+o], 17408B
        float* xs = Wt + 64 * 68;                 // xs[nl*68+k], 34816B
        for (int i = t; i < 64 * 64; i += PXW_THREADS) {
            int o = i >> 6, k = i & 63;
            Wt[k * 68 + o] = W[i];
        }
        int base = ((int)blockIdx.x - pblocks) * 128;
        int row = t >> 4, c4 = (t & 15) * 4;      // row 0..31
        #pragma unroll
        for (int r = 0; r < 4; ++r) {
            int nl = row + r * 32;
            int n = base + nl;
            float4 v = {0.f, 0.f, 0.f, 0.f};
            if (n < N) v = *(const float4*)(x + (size_t)n * 64 + c4);
            *(float4*)&xs[nl * 68 + c4] = v;
        }
        __syncthreads();
        int o4 = (t & 15) * 4, nl4 = (t >> 4) * 4;   // nl4 0..124
        float acc[4][4];
        #pragma unroll
        for (int i = 0; i < 4; ++i)
            #pragma unroll
            for (int j = 0; j < 4; ++j) acc[i][j] = 0.f;
        #pragma unroll 2
        for (int k0 = 0; k0 < 64; k0 += 4) {
            float a[4][4], wv[4][4];
            #pragma unroll
            for (int i = 0; i < 4; ++i)
                *(float4*)a[i] = *(const float4*)&xs[(nl4 + i) * 68 + k0];
            #pragma unroll
            for (int dk = 0; dk < 4; ++dk)
                *(float4*)wv[dk] = *(const float4*)&Wt[(k0 + dk) * 68 + o4];
            #pragma unroll
            for (int i = 0; i < 4; ++i)
                #pragma unroll
                for (int j = 0; j < 4; ++j)
                    acc[i][j] += a[i][0] * wv[0][j] + a[i][1] * wv[1][j]
                               + a[i][2] * wv[2][j] + a[i][3] * wv[3][j];
        }
        int n0 = base + nl4;
        #pragma unroll
        for (int i = 0; i < 4; ++i) {
            if (n0 + i < N) {
                uint2 p;
                p.x = pack_bf16(acc[i][0], acc[i][1]);
                p.y = pack_bf16(acc[i][2], acc[i][3]);
                *(uint2*)(y2 + (size_t)(n0 + i) * 32 + (o4 >> 1)) = p;
            }
        }
    }
}

// accumulate one uint4 (8 bf16 cols) into register set S
#define RACC8(S, u) { \
    S[0] += __uint_as_float((u).x << 16); \
    S[1] += __uint_as_float((u).x & 0xffff0000u); \
    S[2] += __uint_as_float((u).y << 16); \
    S[3] += __uint_as_float((u).y & 0xffff0000u); \
    S[4] += __uint_as_float((u).z << 16); \
    S[5] += __uint_as_float((u).z & 0xffff0000u); \
    S[6] += __uint_as_float((u).w << 16); \
    S[7] += __uint_as_float((u).w & 0xffff0000u); }

// ---- bucket gather: counting-sort + 4-deep register gather --------------
// 8 threads per node, each owns 8 bf16 cols -> one uint4 load per edge.
// 4 loads in flight, 4 independent accumulator sets (register-only).
__global__ __launch_bounds__(GTHREADS) void bucket_gather(
        const unsigned* __restrict__ y2, const unsigned* __restrict__ pairs,
        const int* __restrict__ cursor, const uint2* __restrict__ spill,
        const int* __restrict__ spillCnt,
        const float* __restrict__ deg, const float* __restrict__ b,
        float* __restrict__ out, int N) {
    __shared__ unsigned list[CAP];           // sorted srcs, 4 KB
    __shared__ int cnt[BNODES], st[BNODES], sc[BNODES];
    int t = threadIdx.x;
    int bkt = blockIdx.x, base = bkt << BSHIFT;
    int total = cursor[bkt];
    int cn = total < CAP ? total : CAP;      // slots [0,cn) valid; rest spilled
    int node = t >> 3, c = t & 7;            // 64 nodes x 8 col-octs = 512
    float4 bv0 = ((const float4*)b)[c * 2];
    float4 bv1 = ((const float4*)b)[c * 2 + 1];

    if (t < BNODES) cnt[t] = 0;
    __syncthreads();
    unsigned pv[PERTHREAD];
    #pragma unroll
    for (int j = 0; j < PERTHREAD; ++j) {             // one coalesced pass
        int i = t + j * GTHREADS;
        pv[j] = (i < cn) ? pairs[(size_t)bkt * CAP + i] : 0xFFFFFFFFu;
        if (pv[j] != 0xFFFFFFFFu) atomicAdd(&cnt[pv[j] >> 17], 1);
    }
    __syncthreads();
    if (t < 64) {                            // 64-bin exclusive scan, one wave
        int v = cnt[t];
        #pragma unroll
        for (int off = 1; off < 64; off <<= 1) {
            int u = __shfl_up(v, off);
            if (t >= off) v += u;
        }
        st[t] = v - cnt[t]; sc[t] = v - cnt[t];
    }
    __syncthreads();
    #pragma unroll
    for (int j = 0; j < PERTHREAD; ++j) {             // scatter from registers
        if (pv[j] != 0xFFFFFFFFu) {
            int pos = atomicAdd(&sc[pv[j] >> 17], 1);
            list[pos] = pv[j] & 0x1FFFFu;             // src only
        }
    }
    __syncthreads();

    int scnt = *spillCnt;                             // 0 in practice

    int n = base + node;
    int s0 = st[node], e1 = s0 + cnt[node];
    float sa[8], sb[8], sc_[8], sd[8];
    #pragma unroll
    for (int k = 0; k < 8; ++k) { sa[k] = 0.f; sb[k] = 0.f; sc_[k] = 0.f; sd[k] = 0.f; }
    int i = s0;
    for (; i + 3 < e1; i += 4) {                      // 4 loads in flight
        unsigned v0 = list[i], v1 = list[i + 1];
        unsigned v2 = list[i + 2], v3 = list[i + 3];
        uint4 u0 = *(const uint4*)(y2 + (size_t)v0 * 32 + c * 4);
        uint4 u1 = *(const uint4*)(y2 + (size_t)v1 * 32 + c * 4);
        uint4 u2 = *(const uint4*)(y2 + (size_t)v2 * 32 + c * 4);
        uint4 u3 = *(const uint4*)(y2 + (size_t)v3 * 32 + c * 4);
        RACC8(sa, u0);
        RACC8(sb, u1);
        RACC8(sc_, u2);
        RACC8(sd, u3);
    }
    if (i + 1 < e1) {                                 // pair tail
        unsigned v0 = list[i], v1 = list[i + 1];
        uint4 u0 = *(const uint4*)(y2 + (size_t)v0 * 32 + c * 4);
        uint4 u1 = *(const uint4*)(y2 + (size_t)v1 * 32 + c * 4);
        RACC8(sa, u0);
        RACC8(sb, u1);
        i += 2;
    }
    if (i < e1) {                                     // single tail
        unsigned v0 = list[i];
        uint4 u0 = *(const uint4*)(y2 + (size_t)v0 * 32 + c * 4);
        RACC8(sa, u0);
    }
    #pragma unroll
    for (int k = 0; k < 8; ++k) sa[k] = (sa[k] + sb[k]) + (sc_[k] + sd[k]);
    for (int k = 0; k < scnt; ++k) {                  // overflow path (empty)
        uint2 e = spill[k];
        if ((int)e.y == n) {
            uint4 u = *(const uint4*)(y2 + (size_t)e.x * 32 + c * 4);
            RACC8(sa, u);
        }
    }
    if (n < N) {
        float invd = 1.0f / deg[n];
        float4 o0 = {sa[0] * invd + bv0.x, sa[1] * invd + bv0.y,
                     sa[2] * invd + bv0.z, sa[3] * invd + bv0.w};
        float4 o1 = {sa[4] * invd + bv1.x, sa[5] * invd + bv1.y,
                     sa[6] * invd + bv1.z, sa[7] * invd + bv1.w};
        *(float4*)(out + (size_t)n * 64 + c * 8) = o0;
        *(float4*)(out + (size_t)n * 64 + c * 8 + 4) = o1;
    }
}

// ---- fallback: atomic scatter + LDS GEMM --------------------------------
__global__ __launch_bounds__(256) void scatter_kernel(
        const float* __restrict__ x, const unsigned* __restrict__ ewords,
        float* __restrict__ agg, int E) {
    __shared__ int sflag;
    int s = detect_stride_block(ewords, E, &sflag);
    int gid = blockIdx.x * blockDim.x + threadIdx.x;
    int e = gid >> 4, q = gid & 15;
    if (e >= E) return;
    int src = (int)ewords[(size_t)e * s];
    int dst = (int)ewords[((size_t)E + e) * s];
    const float4 v = *(const float4*)(x + (size_t)src * D + q * 4);
    float* p = agg + (size_t)dst * D + q * 4;
    unsafeAtomicAdd(p + 0, v.x);
    unsafeAtomicAdd(p + 1, v.y);
    unsafeAtomicAdd(p + 2, v.z);
    unsafeAtomicAdd(p + 3, v.w);
}

__global__ __launch_bounds__(256) void gemm_kernel(
        float* __restrict__ inout, const float* __restrict__ deg,
        const float* __restrict__ W, const float* __restrict__ b, int nNodes) {
    __shared__ float Wt[64 * 65];
    __shared__ float rows[4 * 64];
    int t = threadIdx.x;
    for (int i = t; i < 64 * 64; i += 256) {
        int o = i >> 6, k = i & 63;
        Wt[k * 65 + o] = W[i];
    }
    int base = blockIdx.x * 4;
    int nl = t >> 6, o = t & 63;
    int n = base + nl;
    if (n < nNodes) {
        float invd = 1.0f / deg[n];
        rows[nl * 64 + o] = inout[(size_t)n * 64 + o] * invd;
    }
    __syncthreads();
    if (n >= nNodes) return;
    float acc = b[o];
    #pragma unroll
    for (int k = 0; k < 64; ++k)
        acc += rows[nl * 64 + k] * Wt[k * 65 + o];
    inout[(size_t)n * 64 + o] = acc;
}

extern "C" void kernel_launch(void* const* d_in, const int* in_sizes, int n_in,
                              void* d_out, int out_size, void* d_ws, size_t ws_size,
                              hipStream_t stream) {
    const float*    x      = (const float*)d_in[0];
    const unsigned* ewords = (const unsigned*)d_in[1];
    const float*    deg    = (const float*)d_in[2];
    const float*    W      = (const float*)d_in[3];
    const float*    b      = (const float*)d_in[4];
    float*          out    = (float*)d_out;

    const int E = in_sizes[1] / 2;
    const int N = in_sizes[2];
    const int nb = (N + BNODES - 1) >> BSHIFT;         // 1563 for N=100000

    // ws layout: cursor[MAXB] + spillCnt | pairs[nb*CAP] | spill[E] | y2[N*32]
    char* ws = (char*)d_ws;
    size_t curB  = (MAXB + 16) * 4;
    size_t pairB = ((size_t)nb * CAP * 4 + 63) & ~63ull;
    size_t spB   = ((size_t)E * 8 + 63) & ~63ull;
    size_t need  = curB + pairB + spB + (size_t)N * 32 * 4;

    if (ws_size >= need && N < (1 << 17) && nb <= MAXB) {
        int*      cursor   = (int*)ws;
        int*      spillCnt = cursor + MAXB;
        unsigned* pairs    = (unsigned*)(ws + curB);
        uint2*    spill    = (uint2*)(ws + curB + pairB);
        unsigned* y2       = (unsigned*)(ws + curB + pairB + spB);

        hipMemsetAsync(cursor, 0, curB, stream);       // 8KB: cursors + spillCnt

        int pblocks  = (E + 8191) / 8192;
        int xwblocks = (N + 127) / 128;
        partition_xw_kernel<<<pblocks + xwblocks, PXW_THREADS, 0, stream>>>(
            ewords, cursor, pairs, spill, spillCnt, x, W, y2, E, N, nb, pblocks);

        bucket_gather<<<nb, GTHREADS, 0, stream>>>(
            y2, pairs, cursor, spill, spillCnt, deg, b, out, N);
    } else {
        hipMemsetAsync(d_out, 0, (size_t)out_size * sizeof(float), stream);
        long long sthreads = (long long)E * 16;
        int sblocks = (int)((sthreads + 255) / 256);
        scatter_kernel<<<sblocks, 256, 0, stream>>>(x, ewords, out, E);
        gemm_kernel<<<(N + 3) / 4, 256, 0, stream>>>(out, deg, W, b, N);
    }
}